// Round 1
// 224.919 us; speedup vs baseline: 1.0011x; 1.0011x over previous
//
#include <hip/hip_runtime.h>

// GatedCrossModalAttention: B=16384, NM=5, D=256, H=8. FP32 I/O, bf16 internal.
// Attention collapses (Lq=Lk=1 => softmax==1):
//   branch_s(x) = x[:,mod_s] @ (Wo_s@Wv_s)^T + (Wo_s@bv_s+bo_s).
// K1: fuse weights -> WF bf16 [5][256][256] ([out][in]), BF f32 [5][256]  (660 KB ws ONLY)
// K2: fused GEMM+epilogue, 32 rows/block.
// Round-2 lesson: 43 MB Y workspace overflowed ws_size and corrupted pristine inputs
// (first launch passed, all later launches failed). Keep ws usage tiny.
// Round-3 (this): rocprof showed k_main latency-bound (MfmaUtil 4.7%, VALUBusy 16%,
// Occupancy 20.6%) — grid-starved at 8 waves/CU while LDS/VGPR allow 16.
// Switch k_main to 512 threads (8 waves) per 32-row block, same grid 512, same LDS:
// 2 blocks x 8 waves = 16 waves/CU. Per-wave: 32 GEMM cols (2 ct-tiles), 4 epilogue
// rows. Math identical per output element -> absmax unchanged.

typedef __attribute__((ext_vector_type(8))) short short8;
typedef __attribute__((ext_vector_type(4))) float floatx4;

__device__ __forceinline__ float b2f(unsigned short h) {
    union { unsigned int u; float f; } v; v.u = ((unsigned int)h) << 16; return v.f;
}
__device__ __forceinline__ unsigned short f2b(float f) {
    union { unsigned int u; float f; } v; v.f = f;
    unsigned int u = v.u;
    return (unsigned short)((u + 0x7FFFu + ((u >> 16) & 1u)) >> 16);
}

// ---------------- K1: weight fusion ----------------
// grid (64, 5), block 256. Each block: 4 output rows of one branch.
__global__ __launch_bounds__(256) void k_fuse(
    const float* __restrict__ sWi, const float* __restrict__ sbi,
    const float* __restrict__ sWo, const float* __restrict__ sbo,
    const float* __restrict__ cWi, const float* __restrict__ cbi,
    const float* __restrict__ cWo, const float* __restrict__ cbo,
    unsigned short* __restrict__ WF, float* __restrict__ BF)
{
    int s = blockIdx.y;
    int i0 = blockIdx.x * 4;
    int tid = threadIdx.x;
    const float *Wo, *Wv, *bv, *bo;
    if (s == 0) { Wo = sWo; Wv = sWi + 512 * 256; bv = sbi + 512; bo = sbo; }
    else {
        int n = s - 1;
        Wo = cWo + n * 65536;
        Wv = cWi + n * 768 * 256 + 512 * 256;
        bv = cbi + n * 768 + 512;
        bo = cbo + n * 256;
    }
    __shared__ float wo[4 * 256];
    #pragma unroll
    for (int it = 0; it < 4; ++it) {
        int idx = tid + it * 256;
        wo[idx] = Wo[i0 * 256 + idx];
    }
    __syncthreads();
    float a0 = 0.f, a1 = 0.f, a2 = 0.f, a3 = 0.f;
    for (int k = 0; k < 256; ++k) {
        float wv = Wv[k * 256 + tid];
        a0 += wo[k] * wv;
        a1 += wo[256 + k] * wv;
        a2 += wo[512 + k] * wv;
        a3 += wo[768 + k] * wv;
    }
    unsigned short* dst = WF + ((size_t)s * 256 + i0) * 256 + tid;
    dst[0] = f2b(a0); dst[256] = f2b(a1); dst[512] = f2b(a2); dst[768] = f2b(a3);
    if (tid < 4) {
        int i = i0 + tid;
        float bacc = 0.f;
        for (int k = 0; k < 256; ++k) bacc += Wo[i * 256 + k] * bv[k];
        BF[s * 256 + i] = bacc + bo[i];
    }
}

// ---------------- K2: fused GEMM + epilogue ----------------
__device__ __forceinline__ float wred(float v) {
    #pragma unroll
    for (int o = 32; o > 0; o >>= 1) v += __shfl_xor(v, o, 64);
    return v;
}

// grid 512, block 512 (8 waves). Block: rows [b0, b0+32). Wave w: GEMM cols
// [w*32, w*32+32), epilogue rows [w*4, w*4+4) (lane j = lane*4 .. +3).
__global__ __launch_bounds__(512, 4) void k_main(
    const float* __restrict__ x, const unsigned short* __restrict__ WF,
    const float* __restrict__ BF,
    const float* __restrict__ cln_g, const float* __restrict__ cln_b,
    const float* __restrict__ gln_g, const float* __restrict__ gln_b,
    const float* __restrict__ gW, const float* __restrict__ gb,
    const float* __restrict__ fln_g, const float* __restrict__ fln_b,
    const int* __restrict__ midx, float* __restrict__ out)
{
    __shared__ __align__(16) unsigned short A[32 * 264];   // branch A-tile, bf16
    __shared__ __align__(16) unsigned short Yb[32 * 264];  // branch result, bf16
    __shared__ float gWs[5 * 256];
    __shared__ float gLDS[32 * 8];                          // gates per row

    int m = midx[0];
    int b0 = blockIdx.x * 32;
    int tid = threadIdx.x;
    int wave = tid >> 6, lane = tid & 63;
    int l16 = lane & 15, q4 = lane >> 4;
    int j = lane * 4;

    // stage gate weights (1280 floats, 512 threads)
    gWs[tid] = gW[tid];
    gWs[tid + 512] = gW[tid + 512];
    if (tid < 256) gWs[tid + 1024] = gW[tid + 1024];

    // load q rows (fp32, kept in registers for residuals): 4 rows per wave
    float qv[4][4];
    #pragma unroll
    for (int rr = 0; rr < 4; ++rr) {
        int r = wave * 4 + rr;
        float4 u = *(const float4*)(x + ((size_t)(b0 + r) * 5 + m) * 256 + j);
        qv[rr][0] = u.x; qv[rr][1] = u.y; qv[rr][2] = u.z; qv[rr][3] = u.w;
    }
    float4 glg = *(const float4*)(gln_g + j);
    float4 glb = *(const float4*)(gln_b + j);
    float gbv[5];
    #pragma unroll
    for (int n = 0; n < 5; ++n) gbv[n] = gb[n];

    __syncthreads();  // gWs ready

    // gates per row
    #pragma unroll
    for (int rr = 0; rr < 4; ++rr) {
        int r = wave * 4 + rr;
        float s1 = wred(qv[rr][0] + qv[rr][1] + qv[rr][2] + qv[rr][3]);
        float s2 = wred(qv[rr][0]*qv[rr][0] + qv[rr][1]*qv[rr][1] +
                        qv[rr][2]*qv[rr][2] + qv[rr][3]*qv[rr][3]);
        float mn = s1 * (1.f / 256.f);
        float vr = s2 * (1.f / 256.f) - mn * mn;
        float rs = rsqrtf(vr + 1e-5f);
        float qln[4];
        qln[0] = (qv[rr][0] - mn) * rs * glg.x + glb.x;
        qln[1] = (qv[rr][1] - mn) * rs * glg.y + glb.y;
        qln[2] = (qv[rr][2] - mn) * rs * glg.z + glb.z;
        qln[3] = (qv[rr][3] - mn) * rs * glg.w + glb.w;
        float g[5];
        #pragma unroll
        for (int n = 0; n < 5; ++n) {
            float p = qln[0] * gWs[n * 256 + j] + qln[1] * gWs[n * 256 + j + 1]
                    + qln[2] * gWs[n * 256 + j + 2] + qln[3] * gWs[n * 256 + j + 3];
            g[n] = wred(p) + gbv[n];
        }
        float mx = g[0];
        #pragma unroll
        for (int n = 1; n < 5; ++n) mx = fmaxf(mx, g[n]);
        float es = 0.f;
        #pragma unroll
        for (int n = 0; n < 5; ++n) { g[n] = __expf(g[n] - mx); es += g[n]; }
        float inv = 1.f / es;
        if (lane == 0) {
            #pragma unroll
            for (int n = 0; n < 5; ++n) gLDS[r * 8 + n] = g[n] * inv;
        }
    }

    float comb[4][4];
    #pragma unroll
    for (int rr = 0; rr < 4; ++rr)
        #pragma unroll
        for (int i = 0; i < 4; ++i) comb[rr][i] = 0.f;

    for (int s = 0; s < 5; ++s) {
        int mod = (s == 0) ? m : ((s - 1 < m) ? s - 1 : s);
        // stage A: 32 rows x 256 cols of x[:, mod, :], fp32 -> bf16 (2048 float4, 512 thr)
        #pragma unroll
        for (int it = 0; it < 4; ++it) {
            int c = tid + it * 512;
            int row = c >> 6;
            int c4 = (c & 63) << 2;
            float4 v = *(const float4*)(x + ((size_t)(b0 + row) * 5 + mod) * 256 + c4);
            uint2 p;
            p.x = (unsigned int)f2b(v.x) | ((unsigned int)f2b(v.y) << 16);
            p.y = (unsigned int)f2b(v.z) | ((unsigned int)f2b(v.w) << 16);
            *(uint2*)(&A[row * 264 + c4]) = p;
        }
        __syncthreads();  // A ready; also: prev epilogue reads of Yb done before new Yb writes

        // GEMM: 32x256 += A(32x256) * WF_s^T ; wave covers 32 cols
        floatx4 acc[2][2];
        #pragma unroll
        for (int rt = 0; rt < 2; ++rt)
            #pragma unroll
            for (int ct = 0; ct < 2; ++ct) acc[rt][ct] = (floatx4){0.f, 0.f, 0.f, 0.f};
        const unsigned short* wB = WF + (size_t)s * 65536;
        #pragma unroll
        for (int kk = 0; kk < 8; ++kk) {
            int k = kk * 32 + q4 * 8;
            short8 a0 = *(const short8*)(&A[l16 * 264 + k]);
            short8 a1 = *(const short8*)(&A[(16 + l16) * 264 + k]);
            short8 bb[2];
            #pragma unroll
            for (int ct = 0; ct < 2; ++ct)
                bb[ct] = *(const short8*)(wB + (size_t)(wave * 32 + ct * 16 + l16) * 256 + k);
            #pragma unroll
            for (int ct = 0; ct < 2; ++ct) {
                acc[0][ct] = __builtin_amdgcn_mfma_f32_16x16x32_bf16(a0, bb[ct], acc[0][ct], 0, 0, 0);
                acc[1][ct] = __builtin_amdgcn_mfma_f32_16x16x32_bf16(a1, bb[ct], acc[1][ct], 0, 0, 0);
            }
        }
        // park result in LDS (bf16)
        #pragma unroll
        for (int rt = 0; rt < 2; ++rt)
            #pragma unroll
            for (int i = 0; i < 4; ++i) {
                int r = rt * 16 + q4 * 4 + i;
                #pragma unroll
                for (int ct = 0; ct < 2; ++ct)
                    Yb[r * 264 + wave * 32 + ct * 16 + l16] = f2b(acc[rt][ct][i]);
            }
        __syncthreads();  // Yb ready

        // epilogue partial: comb += g_s * (s==0 ? y : LN(q+y))
        float4 bfv = *(const float4*)(BF + s * 256 + j);
        if (s == 0) {
            #pragma unroll
            for (int rr = 0; rr < 4; ++rr) {
                int r = wave * 4 + rr;
                uint2 u = *(const uint2*)(&Yb[r * 264 + j]);
                float y0 = b2f(u.x & 0xffff) + bfv.x, y1 = b2f(u.x >> 16) + bfv.y;
                float y2 = b2f(u.y & 0xffff) + bfv.z, y3 = b2f(u.y >> 16) + bfv.w;
                float g0 = gLDS[r * 8 + 0];
                comb[rr][0] += g0 * y0; comb[rr][1] += g0 * y1;
                comb[rr][2] += g0 * y2; comb[rr][3] += g0 * y3;
            }
        } else {
            float4 cg = *(const float4*)(cln_g + (s - 1) * 256 + j);
            float4 cb = *(const float4*)(cln_b + (s - 1) * 256 + j);
            #pragma unroll
            for (int rr = 0; rr < 4; ++rr) {
                int r = wave * 4 + rr;
                uint2 u = *(const uint2*)(&Yb[r * 264 + j]);
                float t0 = qv[rr][0] + b2f(u.x & 0xffff) + bfv.x;
                float t1 = qv[rr][1] + b2f(u.x >> 16)    + bfv.y;
                float t2 = qv[rr][2] + b2f(u.y & 0xffff) + bfv.z;
                float t3 = qv[rr][3] + b2f(u.y >> 16)    + bfv.w;
                float s1 = wred(t0 + t1 + t2 + t3);
                float s2 = wred(t0*t0 + t1*t1 + t2*t2 + t3*t3);
                float mn = s1 * (1.f / 256.f);
                float vr = s2 * (1.f / 256.f) - mn * mn;
                float rs = rsqrtf(vr + 1e-5f);
                float gs = gLDS[r * 8 + s];
                comb[rr][0] += gs * ((t0 - mn) * rs * cg.x + cb.x);
                comb[rr][1] += gs * ((t1 - mn) * rs * cg.y + cb.y);
                comb[rr][2] += gs * ((t2 - mn) * rs * cg.z + cb.z);
                comb[rr][3] += gs * ((t3 - mn) * rs * cg.w + cb.w);
            }
        }
    }

    // final LN and store
    float4 fg = *(const float4*)(fln_g + j);
    float4 fb = *(const float4*)(fln_b + j);
    #pragma unroll
    for (int rr = 0; rr < 4; ++rr) {
        int r = wave * 4 + rr;
        float t0 = qv[rr][0] + comb[rr][0], t1 = qv[rr][1] + comb[rr][1];
        float t2 = qv[rr][2] + comb[rr][2], t3 = qv[rr][3] + comb[rr][3];
        float s1 = wred(t0 + t1 + t2 + t3);
        float s2 = wred(t0*t0 + t1*t1 + t2*t2 + t3*t3);
        float mn = s1 * (1.f / 256.f);
        float vr = s2 * (1.f / 256.f) - mn * mn;
        float rs = rsqrtf(vr + 1e-5f);
        float4 ov;
        ov.x = (t0 - mn) * rs * fg.x + fb.x;
        ov.y = (t1 - mn) * rs * fg.y + fb.y;
        ov.z = (t2 - mn) * rs * fg.z + fb.z;
        ov.w = (t3 - mn) * rs * fg.w + fb.w;
        *(float4*)(out + (size_t)(b0 + r) * 256 + j) = ov;
    }
}

extern "C" void kernel_launch(void* const* d_in, const int* in_sizes, int n_in,
                              void* d_out, int out_size, void* d_ws, size_t ws_size,
                              hipStream_t stream) {
    const float* x    = (const float*)d_in[0];
    const float* sWi  = (const float*)d_in[1];
    const float* sbi  = (const float*)d_in[2];
    const float* sWo  = (const float*)d_in[3];
    const float* sbo  = (const float*)d_in[4];
    const float* cWi  = (const float*)d_in[5];
    const float* cbi  = (const float*)d_in[6];
    const float* cWo  = (const float*)d_in[7];
    const float* cbo  = (const float*)d_in[8];
    const float* clng = (const float*)d_in[9];
    const float* clnb = (const float*)d_in[10];
    const float* glng = (const float*)d_in[11];
    const float* glnb = (const float*)d_in[12];
    const float* gW   = (const float*)d_in[13];
    const float* gb   = (const float*)d_in[14];
    const float* flng = (const float*)d_in[15];
    const float* flnb = (const float*)d_in[16];
    const int* midx   = (const int*)d_in[17];
    float* out        = (float*)d_out;

    char* ws = (char*)d_ws;
    unsigned short* WF = (unsigned short*)ws;         // 5*256*256*2 = 655360 B
    float* BF          = (float*)(ws + 655360);       // 5*256*4 = 5120 B  (total 660480 B)

    k_fuse<<<dim3(64, 5), 256, 0, stream>>>(sWi, sbi, sWo, sbo, cWi, cbi, cWo, cbo, WF, BF);
    k_main<<<512, 512, 0, stream>>>(x, WF, BF, clng, clnb, glng, glnb, gW, gb, flng, flnb, midx, out);
}